// Round 13
// baseline (185.462 us; speedup 1.0000x reference)
//
#include <hip/hip_runtime.h>
#include <hip/hip_bf16.h>

#define B_ 32
#define T_ 2048
#define D_ 1024
#define A_ 128

typedef __attribute__((ext_vector_type(8))) short bf16x8;
typedef __attribute__((ext_vector_type(4))) float f32x4;

static __device__ __forceinline__ unsigned short f2bf(float f) {
  union { float f; unsigned u; } v; v.f = f;
  unsigned r = v.u + 0x7FFFu + ((v.u >> 16) & 1u);
  return (unsigned short)(r >> 16);
}

// packed f32x2 -> bf16x2 (RNE); compiler emits v_cvt_pk_bf16_f32
static __device__ __forceinline__ unsigned cvt2u(float lo, float hi) {
  __hip_bfloat162 h2 = __float22bfloat162_rn(make_float2(lo, hi));
  unsigned u;
  __builtin_memcpy(&u, &h2, 4);
  return u;
}

// lgkm-only barrier: LDS visibility without draining vmcnt (st/B loads are
// reg-destined; their consumption is enforced by compiler-counted vmcnt at use)
static __device__ __forceinline__ void barrier_lds() {
  asm volatile("s_waitcnt lgkmcnt(0)\n\ts_barrier" ::: "memory");
}

// ---------------- prep: Wt[a][d] = bf16(Ws[d][a]) ----------------
__global__ __launch_bounds__(256) void k_prep(const float* __restrict__ Ws,
                                              unsigned short* __restrict__ Wt) {
  int i = blockIdx.x * 256 + threadIdx.x;  // coalesced write
  int a = i >> 10, d = i & 1023;
  Wt[i] = f2bf(Ws[(size_t)d * A_ + a]);
}

// ---------------- fused: scores -> exp -> weighted x accumulation ----------------
// grid (8, 32): blockIdx.x = t-slice (256 t), blockIdx.y = b. 512 thr (8 waves), 1 blk/CU.
//
// Register discipline (r4-r12): W-in-registers (256 KB/block) never fits any budget ->
// B-frags stream from L2-resident Wt. r10 measured this naively at 80 us: the 32
// B-loads sat on the serial MFMA chain with ~nothing in flight (exposed L2 latency).
// Fix here: 8-deep rotating prefetch buffer (static indices) + dual accumulator
// chains (even/odd kt) -> B-loads issue ~8 MFMAs (~200+ cyc) ahead of use, and the
// MFMA dependency chain halves. Chunk-local opaque asm on the B-pointer blocks LICM
// from hoisting the invariant loads into 128 registers (the r4 spill mechanism).
// Live set ~100 VGPR: st 32 + brot 32 + acc 8 + misc. 1-deep staging (2-deep spills).
#define LDRF 1028  // f32 row stride (4112 B): +16B pad, conflict-free b128/b64
#define LDRB 1032  // bf16 row stride in shorts (2064 B): +16B pad

__global__ __launch_bounds__(512) void k_fused(const float* __restrict__ x,
                                               const unsigned short* __restrict__ Wt,
                                               const float* __restrict__ bs,
                                               const float* __restrict__ us,
                                               float* __restrict__ part,
                                               float* __restrict__ Zp) {
  __shared__ __align__(16) float xb[16 * LDRF];            // 65,792 B (exact f32 chunk)
  __shared__ __align__(16) unsigned short ab[16 * LDRB];   // 33,024 B (bf16 A-buffer)
  __shared__ float sc_part[16 * 8];
  __shared__ float e_lds[16];

  const int tid  = threadIdx.x;
  const int w    = tid >> 6;
  const int lane = tid & 63;
  const int lrow = lane & 15;
  const int g    = lane >> 4;
  const int sub  = blockIdx.x;
  const int b    = blockIdx.y;

  const int a_col = w * 16 + lrow;   // this wave's 16 a-columns
  const float bsv = bs[a_col];
  const float usv = us[a_col];
  const unsigned short* brow = Wt + (size_t)a_col * D_ + g * 8;  // B-frag base (L2)

  // staging: thread owns row srow, 8 float4 at cols scol + q*128 (512B/seg coalesced)
  const int srow = w * 2 + (lane >> 5);
  const int scol = (lane & 31) * 4;
  const float* gx = x + ((size_t)b * T_ + (size_t)sub * 256) * D_;

  float4 st[8];

  // prologue: chunk 0 -> regs -> LDS (f32 + bf16)
#pragma unroll
  for (int q = 0; q < 8; ++q)
    st[q] = *(const float4*)(gx + (size_t)srow * D_ + scol + q * 128);
#pragma unroll
  for (int q = 0; q < 8; ++q) {
    *(float4*)(&xb[srow * LDRF + scol + q * 128]) = st[q];
    unsigned lo = cvt2u(st[q].x, st[q].y);
    unsigned hi = cvt2u(st[q].z, st[q].w);
    *(uint2*)(&ab[srow * LDRB + scol + q * 128]) = make_uint2(lo, hi);
  }
  barrier_lds();

  float a0 = 0.f, a1 = 0.f, zacc = 0.f;

  for (int i = 0; i < 16; ++i) {
    // issue next-chunk staging loads NOW; they land during this chunk's compute
    if (i < 15) {
      const float* gc = gx + (size_t)(i + 1) * 16 * D_;
#pragma unroll
      for (int q = 0; q < 8; ++q)
        st[q] = *(const float4*)(gc + (size_t)srow * D_ + scol + q * 128);
    }
    __builtin_amdgcn_sched_barrier(0);  // pin staging issue above the compute

    // GEMM: z[16 t][16 a-cols of this wave] over K=1024
    // A-frags bf16 from LDS ab; B-frags streamed from L2 with 8-deep prefetch
    const unsigned short* bp = brow;
    asm volatile("" : "+v"(bp));  // opaque per chunk: no cross-chunk hoist of B-loads
    bf16x8 brot[8];
#pragma unroll
    for (int pf = 0; pf < 8; ++pf) brot[pf] = *(const bf16x8*)(bp + pf * 32);
    f32x4 acc0 = (f32x4)0.f, acc1 = (f32x4)0.f;
    const unsigned short* arow = ab + lrow * LDRB + g * 8;
#pragma unroll
    for (int kt = 0; kt < 32; ++kt) {
      bf16x8 af = *(const bf16x8*)(arow + kt * 32);
      bf16x8 bcur = brot[kt & 7];
      if (kt < 24) brot[kt & 7] = *(const bf16x8*)(bp + (kt + 8) * 32);
      if (kt & 1)
        acc1 = __builtin_amdgcn_mfma_f32_16x16x32_bf16(af, bcur, acc1, 0, 0, 0);
      else
        acc0 = __builtin_amdgcn_mfma_f32_16x16x32_bf16(af, bcur, acc0, 0, 0, 0);
    }
    const f32x4 accm = acc0 + acc1;

    // per-wave score partial: sum over this wave's 16 a of us*tanh(z+bs)
    // C layout: col = lane&15 (a), row = g*4 + r (t)
#pragma unroll
    for (int r = 0; r < 4; ++r) {
      float p = usv * tanhf(accm[r] + bsv);
#pragma unroll
      for (int o = 1; o < 16; o <<= 1) p += __shfl_xor(p, o, 64);
      if (lrow == 0) sc_part[(g * 4 + r) * 8 + w] = p;
    }
    barrier_lds();

    // |score| <= ||us||_1 ~ 9 => exp without max-shift is safe in f32
    if (tid < 16) {
      float s = 0.f;
#pragma unroll
      for (int ww = 0; ww < 8; ++ww) s += sc_part[tid * 8 + ww];
      e_lds[tid] = expf(s);
    }
    barrier_lds();

    // exact f32 accumulate: thread owns d = 2*tid, 2*tid+1
    const float* xd = xb + tid * 2;
#pragma unroll
    for (int t = 0; t < 16; ++t) {
      const float2 v = *(const float2*)(xd + t * LDRF);
      const float ev = e_lds[t];
      a0 = fmaf(ev, v.x, a0);
      a1 = fmaf(ev, v.y, a1);
      zacc += ev;  // uniform across threads; thread 0 writes
    }
    barrier_lds();  // all xb/ab reads of chunk i complete

    if (i < 15) {
      // stage chunk i+1 (ds_write waits counted vmcnt on its own loads only)
#pragma unroll
      for (int q = 0; q < 8; ++q) {
        *(float4*)(&xb[srow * LDRF + scol + q * 128]) = st[q];
        unsigned lo = cvt2u(st[q].x, st[q].y);
        unsigned hi = cvt2u(st[q].z, st[q].w);
        *(uint2*)(&ab[srow * LDRB + scol + q * 128]) = make_uint2(lo, hi);
      }
      barrier_lds();
    }
  }

  float* pp = part + ((size_t)sub * B_ + b) * D_ + tid * 2;
  *(float2*)pp = make_float2(a0, a1);
  if (tid == 0) Zp[b * 8 + sub] = zacc;
}

// ---------------- reduce 8 slice-partials, divide by Z ----------------
__global__ __launch_bounds__(256) void k_reduce(const float* __restrict__ part,
                                                const float* __restrict__ Zp,
                                                float* __restrict__ out) {
  const int i = blockIdx.x * 256 + threadIdx.x;  // 0..32767
  const int b = i >> 10, d = i & 1023;
  float zs = 0.f;
#pragma unroll
  for (int s = 0; s < 8; ++s) zs += Zp[b * 8 + s];
  float acc = 0.f;
#pragma unroll
  for (int s = 0; s < 8; ++s) acc += part[((size_t)s * B_ + b) * D_ + d];
  out[i] = acc / zs;
}

extern "C" void kernel_launch(void* const* d_in, const int* in_sizes, int n_in,
                              void* d_out, int out_size, void* d_ws, size_t ws_size,
                              hipStream_t stream) {
  const float* x  = (const float*)d_in[0];
  const float* Ws = (const float*)d_in[1];
  const float* bs = (const float*)d_in[2];
  const float* us = (const float*)d_in[3];
  float* out = (float*)d_out;

  char* ws = (char*)d_ws;
  unsigned short* Wt = (unsigned short*)ws;                 // 256 KB
  float* part = (float*)(ws + (256 << 10));                 // 1 MB
  float* Zp   = (float*)(ws + (256 << 10) + (1 << 20));     // 1 KB

  k_prep<<<512, 256, 0, stream>>>(Ws, Wt);
  k_fused<<<dim3(8, B_), 512, 0, stream>>>(x, Wt, bs, us, part, Zp);
  k_reduce<<<(B_ * D_) / 256, 256, 0, stream>>>(part, Zp, out);
}